// Round 13
// baseline (138.984 us; speedup 1.0000x reference)
//
#include <hip/hip_runtime.h>

typedef unsigned short u16;
typedef unsigned int u32;
typedef __bf16 bf16x8 __attribute__((ext_vector_type(8)));
typedef __bf16 bf16x2 __attribute__((ext_vector_type(2)));
typedef float f32x4 __attribute__((ext_vector_type(4)));
typedef float f32x2 __attribute__((ext_vector_type(2)));
typedef u32 u32x4 __attribute__((ext_vector_type(4)));
typedef u32 u32x2 __attribute__((ext_vector_type(2)));

#define DEVI __device__ __forceinline__

#if defined(__has_builtin)
#if __has_builtin(__builtin_amdgcn_exp2f)
#define EXP2F(x) __builtin_amdgcn_exp2f(x)
#endif
#endif
#ifndef EXP2F
#define EXP2F(x) exp2f(x)
#endif

#define MFMA16(a, b, c) __builtin_amdgcn_mfma_f32_16x16x32_bf16(a, b, c, 0, 0, 0)

typedef __attribute__((address_space(1))) u32 gu32;
typedef __attribute__((address_space(3))) u32 lu32;
DEVI void gll16(const u16* g, u16* l) {
    __builtin_amdgcn_global_load_lds((const gu32*)g, (lu32*)l, 16, 0, 0);
}
#define WAIT_VM0() __builtin_amdgcn_s_waitcnt(0x0f70)  // vmcnt(0) only

DEVI u16 f2bf(float f) {
    u32 u = __builtin_bit_cast(u32, f);
    u = (u + 0x7FFFu + ((u >> 16) & 1u)) >> 16;
    return (u16)u;
}
DEVI float bf2f(u16 h) {
    u32 u = ((u32)h) << 16;
    return __builtin_bit_cast(float, u);
}
DEVI float bfhi(u32 u) { return __builtin_bit_cast(float, u & 0xFFFF0000u); }
DEVI float bflo(u32 u) { return __builtin_bit_cast(float, u << 16); }
DEVI bf16x8 bc8(u32x4 u) { return __builtin_bit_cast(bf16x8, u); }
DEVI u32 pack2(float a, float b) {
    f32x2 v = {a, b};
    bf16x2 h = __builtin_convertvector(v, bf16x2);
    return __builtin_bit_cast(u32, h);
}

// q scale: dh^-0.5 * log2(e)  (bakes natural-exp into exp2)
#define QSCALE 0.18033688011112042f

// ---------------------------------------------------------------------------
// K0: weight/rel-table bf16 conversion ONLY (256 blocks). The x-transpose was
// folded into k_qkv (R13): it occupied 512 blocks + a 4 MB xt write + ~48 MB
// of xt re-reads + a full kernel-drain boundary on the critical path.
__global__ __launch_bounds__(256) void k_prep(const float* __restrict__ wq,
                                              const float* __restrict__ wo,
                                              const float* __restrict__ relh,
                                              const float* __restrict__ relw,
                                              u16* __restrict__ wqb, u16* __restrict__ wob,
                                              u16* __restrict__ relhb, u16* __restrict__ relwb) {
    int i0 = blockIdx.x * 256 + threadIdx.x;  // 65536 stride
#pragma unroll
    for (int i = i0; i < 196608; i += 65536) wqb[i] = f2bf(wq[i]);
    if (i0 < 65536) wob[i0] = f2bf(wo[i0]);
    if (i0 < 8192) {
        relhb[i0] = (i0 < 8128) ? f2bf(relh[i0]) : (u16)0;
        relwb[i0] = (i0 < 8128) ? f2bf(relw[i0]) : (u16)0;
    }
}

// ---------------------------------------------------------------------------
// K1: QKV projection GEMM + fused rel-bias tables. A-fragments now built
// DIRECTLY from x (fused transpose+cast through the Sm LDS buffer, 4 rounds
// of 64c x 64p f32 tiles -- k_prep's proven pattern), then Sm is reused for
// the gll-staged B-tile. Height table stored TRANSPOSED via LDS + coalesced.
__global__ __launch_bounds__(256) void k_qkv(const float* __restrict__ x,
                                             const u16* __restrict__ wqb,
                                             const u16* __restrict__ relwb,
                                             const u16* __restrict__ relhb,
                                             u16* __restrict__ q, u16* __restrict__ k,
                                             u16* __restrict__ vt, u16* __restrict__ Wabs,
                                             u16* __restrict__ HabsT) {
    int pm = blockIdx.x, on = blockIdx.y, b = blockIdx.z;
    int p0 = pm * 64, o0 = on * 64;
    __shared__ __align__(16) u16 Sm[64 * 256];  // 32 KB: f32 staging, B-tile, T/Ls
    int t = threadIdx.x;
    int wv = t >> 6, l = t & 63, quad = l >> 4, li = l & 15;

    // ---- fused x transpose+cast -> areg (A fragments) ----
    // areg[kc] = 8 bf16 of row p = wv*16+li, cols c = kc*32 + quad*8 + 0..7
    u32x4 areg[8];
    {
        float* Sf = (float*)Sm;  // [64 c][65 p] staging tile (16.6 KB)
        int pr = wv * 16 + li;   // this thread's p-row within tile
#pragma unroll
        for (int cm = 0; cm < 4; ++cm) {
            if (cm) __syncthreads();  // prior extract reads done
#pragma unroll
            for (int it = 0; it < 4; ++it) {
                int idx = it * 256 + t;
                int cl = idx >> 4, f4 = idx & 15;
                f32x4 v = *(const f32x4*)(x + ((size_t)(b * 256 + cm * 64 + cl)) * 4096 + p0 +
                                          f4 * 4);
                Sf[cl * 65 + f4 * 4 + 0] = v[0];
                Sf[cl * 65 + f4 * 4 + 1] = v[1];
                Sf[cl * 65 + f4 * 4 + 2] = v[2];
                Sf[cl * 65 + f4 * 4 + 3] = v[3];
            }
            __syncthreads();
#pragma unroll
            for (int kk = 0; kk < 2; ++kk) {
                const float* src = Sf + (kk * 32 + quad * 8) * 65 + pr;
                u32x4 pk;
                pk.x = pack2(src[0 * 65], src[1 * 65]);
                pk.y = pack2(src[2 * 65], src[3 * 65]);
                pk.z = pack2(src[4 * 65], src[5 * 65]);
                pk.w = pack2(src[6 * 65], src[7 * 65]);
                areg[cm * 2 + kk] = pk;
            }
        }
        __syncthreads();  // all extracts done before B staging overwrites Sm
    }

    {
        int pc = l & 31;
#pragma unroll
        for (int i = 0; i < 8; ++i) {
            int r = wv * 16 + i * 2 + (l >> 5);
            gll16(wqb + (size_t)(o0 + r) * 256 + ((pc + r) & 31) * 8,
                  Sm + (wv * 16 + i * 2) * 256);
        }
    }
    WAIT_VM0();
    __syncthreads();

    f32x4 acc[4] = {{0, 0, 0, 0}, {0, 0, 0, 0}, {0, 0, 0, 0}, {0, 0, 0, 0}};
#pragma unroll
    for (int kc = 0; kc < 8; ++kc) {
        bf16x8 a = bc8(areg[kc]);
#pragma unroll
        for (int ct = 0; ct < 4; ++ct) {
            bf16x8 bb = bc8(*(const u32x4*)(Sm + (ct * 16 + li) * 256 +
                                            (((kc * 4 + quad) - (ct * 16 + li)) & 31) * 8));
            acc[ct] = MFMA16(a, bb, acc[ct]);
        }
    }

    int tensor = on >> 2, head = on & 3;
    if (tensor == 2) {
        __syncthreads();
        u16* T = Sm;  // [64 d][72 p]
#pragma unroll
        for (int ct = 0; ct < 4; ++ct)
#pragma unroll
            for (int r = 0; r < 4; ++r)
                T[(ct * 16 + li) * 72 + wv * 16 + quad * 4 + r] = f2bf(acc[ct][r]);
        __syncthreads();
        int dr = t >> 2, pc = (t & 3) * 16;
        u32x4* g = (u32x4*)(vt + ((size_t)((b * 4 + head) * 64 + dr)) * 4096 + p0 + pc);
        const u32x4* s2 = (const u32x4*)(T + dr * 72 + pc);
        g[0] = s2[0];
        g[1] = s2[1];
    } else {
        u16* outp = (tensor == 0) ? q : k;
        float sc = (tensor == 0) ? QSCALE : 1.0f;
#pragma unroll
        for (int ct = 0; ct < 4; ++ct)
#pragma unroll
            for (int r = 0; r < 4; ++r) {
                int p = p0 + wv * 16 + quad * 4 + r;
                int d = ct * 16 + li;
                outp[((size_t)((b * 4 + head) * 4096 + p)) * 64 + d] = f2bf(acc[ct][r] * sc);
            }
        if (tensor == 0) {
            // ---- fused rel-bias tables ----
            int bh = b * 4 + head;
            u16* T = Sm;             // [64 p][72 d]
            u16* Ls = Sm + 64 * 72;  // [128 r][72 d]
            __syncthreads();  // all GEMM Sm reads done
#pragma unroll
            for (int ct = 0; ct < 4; ++ct)
#pragma unroll
                for (int r = 0; r < 4; ++r)
                    T[(wv * 16 + quad * 4 + r) * 72 + ct * 16 + li] = f2bf(acc[ct][r] * QSCALE);
            {
                int row = t >> 1, half = t & 1;
                const u32x4* g2 = (const u32x4*)(relwb + row * 64 + half * 32);
                u32x4* s2 = (u32x4*)(Ls + row * 72 + half * 32);
#pragma unroll
                for (int kk = 0; kk < 4; ++kk) s2[kk] = g2[kk];
            }
            __syncthreads();
            u32x4 aq2[2];
            aq2[0] = *(const u32x4*)(T + (wv * 16 + li) * 72 + quad * 8);
            aq2[1] = *(const u32x4*)(T + (wv * 16 + li) * 72 + 32 + quad * 8);

            f32x4 acc2[8];
#pragma unroll
            for (int ct = 0; ct < 8; ++ct) acc2[ct] = (f32x4){0.f, 0.f, 0.f, 0.f};
#pragma unroll
            for (int kc = 0; kc < 2; ++kc) {
                bf16x8 a = bc8(aq2[kc]);
#pragma unroll
                for (int ct = 0; ct < 8; ++ct) {
                    bf16x8 bb = bc8(*(const u32x4*)(Ls + (ct * 16 + li) * 72 + kc * 32 + quad * 8));
                    acc2[ct] = MFMA16(a, bb, acc2[ct]);
                }
            }
#pragma unroll
            for (int ct = 0; ct < 8; ++ct)
#pragma unroll
                for (int r = 0; r < 4; ++r) {
                    int row = wv * 16 + quad * 4 + r;
                    int j = (ct * 16 + li) - 63 + row;  // shift = y = row
                    if (j >= 0 && j < 64)
                        Wabs[((size_t)(bh * 4096 + p0 + row)) * 64 + j] = f2bf(acc2[ct][r]);
                }
            __syncthreads();  // Ls reads done
            {
                int row = t >> 1, half = t & 1;
                const u32x4* g2 = (const u32x4*)(relhb + row * 64 + half * 32);
                u32x4* s2 = (u32x4*)(Ls + row * 72 + half * 32);
#pragma unroll
                for (int kk = 0; kk < 4; ++kk) s2[kk] = g2[kk];
            }
            __syncthreads();
#pragma unroll
            for (int ct = 0; ct < 8; ++ct) acc2[ct] = (f32x4){0.f, 0.f, 0.f, 0.f};
#pragma unroll
            for (int kc = 0; kc < 2; ++kc) {
                bf16x8 a = bc8(aq2[kc]);
#pragma unroll
                for (int ct = 0; ct < 8; ++ct) {
                    bf16x8 bb = bc8(*(const u32x4*)(Ls + (ct * 16 + li) * 72 + kc * 32 + quad * 8));
                    acc2[ct] = MFMA16(a, bb, acc2[ct]);
                }
            }
            // transpose height bias in LDS (reuse dead T region), then store
            // HabsT[bh][jh][p] with coalesced u32x4 stores (vt-path pattern).
            u16* Ht = Sm;  // [64 j][72 p]
#pragma unroll
            for (int ct = 0; ct < 8; ++ct)
#pragma unroll
                for (int r = 0; r < 4; ++r) {
                    int row = wv * 16 + quad * 4 + r;
                    int j = (ct * 16 + li) - 63 + pm;  // shift = x = pm
                    if (j >= 0 && j < 64) Ht[j * 72 + row] = f2bf(acc2[ct][r]);
                }
            __syncthreads();
            {
                int jr = t >> 2, pc2 = (t & 3) * 16;
                u32x4* g2 = (u32x4*)(HabsT + ((size_t)(bh * 64 + jr)) * 4096 + p0 + pc2);
                const u32x4* s2 = (const u32x4*)(Ht + jr * 72 + pc2);
                g2[0] = s2[0];
                g2[1] = s2[1];
            }
        }
    }
}

// ---------------------------------------------------------------------------
// K3: flash attention (R11 banked best: 49.2us, VGPR 124, 0 conflicts, no
// spill). 4 rs/wave, gll staging + XOR slot-swizzle, grid (16,8,4). All
// scheduling levers measured-dead: occupancy (R2/R6/R10), P-pipelining (R8),
// barrier-halving (R12). Latency-bound plateau; structure frozen.
__global__ __launch_bounds__(256, 2) void k_flash(const u16* __restrict__ q,
                                                  const u16* __restrict__ kg,
                                                  const u16* __restrict__ vt,
                                                  const u16* __restrict__ Wabs,
                                                  const u16* __restrict__ HabsT,
                                                  u16* __restrict__ OP,
                                                  float* __restrict__ LS) {
    int pm = blockIdx.x, bh = blockIdx.y, ks = blockIdx.z;  // ks in 0..3
    int p0 = pm * 256;
    __shared__ __align__(16) u16 Kt[2][64 * 64];
    __shared__ __align__(16) u16 Vl[2][64 * 64];
    int t = threadIdx.x, wv = t >> 6, l = t & 63, quad = l >> 4, li = l & 15;
    int rbase = wv * 64;

    // Q B-frags for all four row-sets
    u32x4 aq[4][2];
#pragma unroll
    for (int rs = 0; rs < 4; ++rs) {
        const u32x4* qrow =
            (const u32x4*)(q + ((size_t)(bh * 4096 + p0 + rbase + rs * 16 + li)) * 64);
        aq[rs][0] = qrow[quad];
        aq[rs][1] = qrow[4 + quad];
    }

    // width-bias UNPACKED f32x4 per (rs,ct); C-frag slot (ct,quad,r) holds
    // original jw = (ct>>1)*32 + quad*8 + (ct&1)*4 + r  (sigma mapping)
    f32x4 wb4[4][4];
#pragma unroll
    for (int rs = 0; rs < 4; ++rs)
#pragma unroll
        for (int ct = 0; ct < 4; ++ct) {
            int jcol = ((ct >> 1) * 32) + quad * 8 + ((ct & 1) * 4);
            const u32* wp = (const u32*)(Wabs +
                                         ((size_t)(bh * 4096 + p0 + rbase + rs * 16 + li)) * 64 +
                                         jcol);
            u32 lo = wp[0], hi = wp[1];
            wb4[rs][ct] = (f32x4){bflo(lo), bfhi(lo), bflo(hi), bfhi(hi)};
        }

    // height-bias source: HabsT[bh][jh][p]
    const u16* hbase = HabsT + ((size_t)(bh * 64 + ks * 16)) * 4096 + p0 + rbase;

    // gll source mapping: lane l writes LDS phys row R = n*32 + wv*8 + (l>>3),
    // 16B slot (l&7). K: global row sigma^-1(R), col slot (l&7)^(l>>3).
    int ln3 = l >> 3, ln7 = l & 7;
    int xo = (ln7 ^ ln3) * 8;  // u16 col offset
    int R0 = wv * 8 + ln3, R1 = 32 + R0;
    int j0r = (R0 & 32) | ((R0 & 16) >> 2) | ((R0 & 8) << 1) | ((R0 & 4) << 1) | (R0 & 3);
    int j1r = (R1 & 32) | ((R1 & 16) >> 2) | ((R1 & 8) << 1) | ((R1 & 4) << 1) | (R1 & 3);
    const u16* kS0 = kg + ((size_t)(bh * 4096 + ks * 1024 + j0r)) * 64 + xo;
    const u16* kS1 = kg + ((size_t)(bh * 4096 + ks * 1024 + j1r)) * 64 + xo;
    const u16* vS0 = vt + ((size_t)(bh * 64 + R0)) * 4096 + ks * 1024 + xo;
    const u16* vS1 = vt + ((size_t)(bh * 64 + R1)) * 4096 + ks * 1024 + xo;
    int ldst = wv * 512;  // wave-uniform LDS u16 offset (call n adds n*2048)

    // ds_read offsets: addr = row*64 + ((grp)^(row&7))*8 ; row = blk*16+li
    int o0 = li * 64 + ((quad ^ ln7) * 8);        // kc/half = 0
    int o1 = li * 64 + (((quad + 4) ^ ln7) * 8);  // kc/half = 1

    // preload tile 0 into buffer 0
    gll16(kS0, Kt[0] + ldst);
    gll16(kS1, Kt[0] + 2048 + ldst);
    gll16(vS0, Vl[0] + ldst);
    gll16(vS1, Vl[0] + 2048 + ldst);
    u16 hc[4];
#pragma unroll
    for (int rs = 0; rs < 4; ++rs) hc[rs] = hbase[rs * 16 + li];
    WAIT_VM0();

    f32x4 oacc[4][5];
#pragma unroll
    for (int rs = 0; rs < 4; ++rs)
#pragma unroll
        for (int ct = 0; ct < 5; ++ct) oacc[rs][ct] = (f32x4){0.f, 0.f, 0.f, 0.f};

    const u32x4 ones = {0x3F803F80u, 0x3F803F80u, 0x3F803F80u, 0x3F803F80u};

    for (int kt = 0; kt < 16; ++kt) {
        __syncthreads();  // tile kt ready in buf[kt&1]; prior reads of buf[kt^1] done
        int cur = kt & 1;
        const u16* Kc = Kt[cur];
        const u16* Vc = Vl[cur];
        u16 hn[4];
        if (kt < 15) {
            kS0 += 4096;
            kS1 += 4096;
            vS0 += 64;
            vS1 += 64;
            u16* Kn = Kt[cur ^ 1];
            u16* Vn = Vl[cur ^ 1];
            gll16(kS0, Kn + ldst);
            gll16(kS1, Kn + 2048 + ldst);
            gll16(vS0, Vn + ldst);
            gll16(vS1, Vn + 2048 + ldst);
#pragma unroll
            for (int rs = 0; rs < 4; ++rs) hn[rs] = hbase[(size_t)(kt + 1) * 4096 + rs * 16 + li];
        }

        // hoisted per-iter height-bias converts (4 instead of 16)
        float hh[4];
#pragma unroll
        for (int rs = 0; rs < 4; ++rs) hh[rs] = bf2f(hc[rs]);

        // S^T = K · Q^T (bias-init accumulators), exp2 + pack per (ct,rs)
        u32x4 pf[4][2];
#pragma unroll
        for (int ct = 0; ct < 4; ++ct) {
            bf16x8 af0 = bc8(*(const u32x4*)(Kc + ct * 1024 + o0));
            bf16x8 af1 = bc8(*(const u32x4*)(Kc + ct * 1024 + o1));
#pragma unroll
            for (int rs = 0; rs < 4; ++rs) {
                f32x4 hv = {hh[rs], hh[rs], hh[rs], hh[rs]};
                f32x4 s4 = wb4[rs][ct] + hv;
                s4 = MFMA16(af0, bc8(aq[rs][0]), s4);
                s4 = MFMA16(af1, bc8(aq[rs][1]), s4);
                u32 pa = pack2(EXP2F(s4[0]), EXP2F(s4[1]));
                u32 pb = pack2(EXP2F(s4[2]), EXP2F(s4[3]));
                if (ct & 1) {
                    pf[rs][ct >> 1].z = pa;
                    pf[rs][ct >> 1].w = pb;
                } else {
                    pf[rs][ct >> 1].x = pa;
                    pf[rs][ct >> 1].y = pb;
                }
            }
        }

        // O += P · V via MFMA16 (K=32); setprio(1) around the MFMA cluster
        __builtin_amdgcn_s_setprio(1);
#pragma unroll
        for (int dt = 0; dt < 4; ++dt) {
            bf16x8 B0 = bc8(*(const u32x4*)(Vc + dt * 1024 + o0));
            bf16x8 B1 = bc8(*(const u32x4*)(Vc + dt * 1024 + o1));
#pragma unroll
            for (int rs = 0; rs < 4; ++rs) {
                oacc[rs][dt] = MFMA16(bc8(pf[rs][0]), B0, oacc[rs][dt]);
                oacc[rs][dt] = MFMA16(bc8(pf[rs][1]), B1, oacc[rs][dt]);
            }
        }
        // row sums via ones operand
#pragma unroll
        for (int rs = 0; rs < 4; ++rs) {
            oacc[rs][4] = MFMA16(bc8(pf[rs][0]), bc8(ones), oacc[rs][4]);
            oacc[rs][4] = MFMA16(bc8(pf[rs][1]), bc8(ones), oacc[rs][4]);
        }
        __builtin_amdgcn_s_setprio(0);

        if (kt < 15) {
            WAIT_VM0();  // gll writes to buf[cur^1] + hn loads landed
#pragma unroll
            for (int rs = 0; rs < 4; ++rs) hc[rs] = hn[rs];
        }
    }

    // store bf16 partials + fp32 row-sums (normalization in k_out2)
#pragma unroll
    for (int rs = 0; rs < 4; ++rs) {
#pragma unroll
        for (int ct = 0; ct < 4; ++ct)
#pragma unroll
            for (int r = 0; r < 4; ++r) {
                int p = p0 + rbase + rs * 16 + quad * 4 + r;
                OP[((size_t)((ks * 8 + bh) * 4096 + p)) * 64 + ct * 16 + li] =
                    f2bf(oacc[rs][ct][r]);
            }
        if (li == 0) {
#pragma unroll
            for (int r = 0; r < 4; ++r) {
                int p = p0 + rbase + rs * 16 + quad * 4 + r;
                LS[(size_t)(ks * 8 + bh) * 4096 + p] = oacc[rs][4][r];
            }
        }
    }
}

// ---------------------------------------------------------------------------
// K4: fused combine (4 K-slices) + out-projection + residual, v2.
// p split 128-way (32-row tiles), grid (128 pm, 2 b, 2 coh) = 512 blocks.
__global__ __launch_bounds__(256) void k_out2(const u16* __restrict__ wob,
                                              const u16* __restrict__ OP,
                                              const float* __restrict__ LS,
                                              const float* __restrict__ x,
                                              float* __restrict__ out) {
    int pm = blockIdx.x, b = blockIdx.y, coh = blockIdx.z;
    int p0 = pm * 32;
    __shared__ __align__(16) u16 Bt[32 * 264];
    int t = threadIdx.x, wv = t >> 6, l = t & 63, quad = l >> 4, li = l & 15;

    {
        int row = t >> 3, head = (t >> 1) & 3, hf = t & 1;
        int bh = b * 4 + head;
        int p = p0 + row;
        const u32x4* o0p = (const u32x4*)(OP + ((size_t)(bh * 4096 + p)) * 64) + hf * 4;
        const u32x4* o1p = (const u32x4*)(OP + ((size_t)((8 + bh) * 4096 + p)) * 64) + hf * 4;
        const u32x4* o2p = (const u32x4*)(OP + ((size_t)((16 + bh) * 4096 + p)) * 64) + hf * 4;
        const u32x4* o3p = (const u32x4*)(OP + ((size_t)((24 + bh) * 4096 + p)) * 64) + hf * 4;
        float linv = 1.0f / (LS[(size_t)bh * 4096 + p] + LS[(size_t)(8 + bh) * 4096 + p] +
                             LS[(size_t)(16 + bh) * 4096 + p] + LS[(size_t)(24 + bh) * 4096 + p]);
        u16* dst = Bt + row * 264 + head * 64 + hf * 32;
#pragma unroll
        for (int kk = 0; kk < 4; ++kk) {
            u32x4 a = o0p[kk], c = o1p[kk], d = o2p[kk], e = o3p[kk];
            u32x4 pk;
            pk.x = pack2((bflo(a.x) + bflo(c.x) + bflo(d.x) + bflo(e.x)) * linv,
                         (bfhi(a.x) + bfhi(c.x) + bfhi(d.x) + bfhi(e.x)) * linv);
            pk.y = pack2((bflo(a.y) + bflo(c.y) + bflo(d.y) + bflo(e.y)) * linv,
                         (bfhi(a.y) + bfhi(c.y) + bfhi(d.y) + bfhi(e.y)) * linv);
            pk.z = pack2((bflo(a.z) + bflo(c.z) + bflo(d.z) + bflo(e.z)) * linv,
                         (bfhi(a.z) + bfhi(c.z) + bfhi(d.z) + bfhi(e.z)) * linv);
            pk.w = pack2((bflo(a.w) + bflo(c.w) + bflo(d.w) + bflo(e.w)) * linv,
                         (bfhi(a.w) + bfhi(c.w) + bfhi(d.w) + bfhi(e.w)) * linv);
            *(u32x4*)(dst + kk * 8) = pk;
        }
    }
    __syncthreads();

#pragma unroll
    for (int ci = 0; ci < 2; ++ci) {
        int com = coh * 2 + ci;
        int co0 = com * 64;
        f32x4 acc[2] = {{0, 0, 0, 0}, {0, 0, 0, 0}};
        const u32x4* arow = (const u32x4*)(wob + (size_t)(co0 + wv * 16 + li) * 256);
#pragma unroll
        for (int kc = 0; kc < 8; ++kc) {
            bf16x8 a = bc8(arow[kc * 4 + quad]);
#pragma unroll
            for (int ct = 0; ct < 2; ++ct) {
                bf16x8 bb = bc8(*(const u32x4*)(Bt + (ct * 16 + li) * 264 + kc * 32 + quad * 8));
                acc[ct] = MFMA16(a, bb, acc[ct]);
            }
        }
#pragma unroll
        for (int ct = 0; ct < 2; ++ct)
#pragma unroll
            for (int r = 0; r < 4; ++r) {
                size_t idx =
                    ((size_t)(b * 256 + co0 + wv * 16 + quad * 4 + r)) * 4096 + p0 + ct * 16 + li;
                out[idx] = acc[ct][r] + x[idx];
            }
    }
}

// ---------------------------------------------------------------------------
extern "C" void kernel_launch(void* const* d_in, const int* in_sizes, int n_in, void* d_out,
                              int out_size, void* d_ws, size_t ws_size, hipStream_t stream) {
    const float* x = (const float*)d_in[0];
    const float* wqkv = (const float*)d_in[1];
    const float* wout = (const float*)d_in[2];
    const float* relh = (const float*)d_in[3];
    const float* relw = (const float*)d_in[4];
    float* out = (float*)d_out;
    char* ws = (char*)d_ws;

    u16* wqb = (u16*)(ws + 4194304);        //   393,216
    u16* wob = (u16*)(ws + 4587520);        //   131,072
    u16* relwb = (u16*)(ws + 4718592);      //    16,384
    u16* relhb = (u16*)(ws + 4734976);      //    16,384
    u16* qb = (u16*)(ws + 4751360);         // 4,194,304
    u16* kb = (u16*)(ws + 8945664);         // 4,194,304
    u16* vtb = (u16*)(ws + 13139968);       // 4,194,304
    u16* Wabs = (u16*)(ws + 17334272);      // 4,194,304
    u16* HabsT = (u16*)(ws + 21528576);     // 4,194,304
    u16* OPart = (u16*)(ws + 25722880);     // 16,777,216 (4 x 8 x 4096 x 64 bf16)
    float* LSum = (float*)(ws + 0);         //   524,288 (xt region now free)

    k_prep<<<256, 256, 0, stream>>>(wqkv, wout, relh, relw, wqb, wob, relhb, relwb);
    k_qkv<<<dim3(64, 12, 2), 256, 0, stream>>>(x, wqb, relwb, relhb, qb, kb, vtb, Wabs, HabsT);
    k_flash<<<dim3(16, 8, 4), 256, 0, stream>>>(qb, kb, vtb, Wabs, HabsT, OPart, LSum);
    k_out2<<<dim3(128, 2, 2), 256, 0, stream>>>(wob, OPart, LSum, x, out);
}

// Round 14
// 134.239 us; speedup vs baseline: 1.0353x; 1.0353x over previous
//
#include <hip/hip_runtime.h>

typedef unsigned short u16;
typedef unsigned int u32;
typedef __bf16 bf16x8 __attribute__((ext_vector_type(8)));
typedef __bf16 bf16x2 __attribute__((ext_vector_type(2)));
typedef float f32x4 __attribute__((ext_vector_type(4)));
typedef float f32x2 __attribute__((ext_vector_type(2)));
typedef u32 u32x4 __attribute__((ext_vector_type(4)));
typedef u32 u32x2 __attribute__((ext_vector_type(2)));

#define DEVI __device__ __forceinline__

#if defined(__has_builtin)
#if __has_builtin(__builtin_amdgcn_exp2f)
#define EXP2F(x) __builtin_amdgcn_exp2f(x)
#endif
#endif
#ifndef EXP2F
#define EXP2F(x) exp2f(x)
#endif

#define MFMA16(a, b, c) __builtin_amdgcn_mfma_f32_16x16x32_bf16(a, b, c, 0, 0, 0)

typedef __attribute__((address_space(1))) u32 gu32;
typedef __attribute__((address_space(3))) u32 lu32;
DEVI void gll16(const u16* g, u16* l) {
    __builtin_amdgcn_global_load_lds((const gu32*)g, (lu32*)l, 16, 0, 0);
}
#define WAIT_VM0() __builtin_amdgcn_s_waitcnt(0x0f70)  // vmcnt(0) only

DEVI u16 f2bf(float f) {
    u32 u = __builtin_bit_cast(u32, f);
    u = (u + 0x7FFFu + ((u >> 16) & 1u)) >> 16;
    return (u16)u;
}
DEVI float bf2f(u16 h) {
    u32 u = ((u32)h) << 16;
    return __builtin_bit_cast(float, u);
}
DEVI float bfhi(u32 u) { return __builtin_bit_cast(float, u & 0xFFFF0000u); }
DEVI float bflo(u32 u) { return __builtin_bit_cast(float, u << 16); }
DEVI bf16x8 bc8(u32x4 u) { return __builtin_bit_cast(bf16x8, u); }
DEVI u32 pack2(float a, float b) {
    f32x2 v = {a, b};
    bf16x2 h = __builtin_convertvector(v, bf16x2);
    return __builtin_bit_cast(u32, h);
}

// q scale: dh^-0.5 * log2(e)  (bakes natural-exp into exp2)
#define QSCALE 0.18033688011112042f

// ---------------------------------------------------------------------------
// K0: fused prep, vectorized (R12 version restored -- xt round-trip measured
// cheaper than 12x f32 re-reads in R13). Blocks [0,512): transpose+cast
// x -> xt[b][p][c]. Blocks [512,768): weights.
__global__ __launch_bounds__(256) void k_prep(const float* __restrict__ x,
                                              const float* __restrict__ wq,
                                              const float* __restrict__ wo,
                                              const float* __restrict__ relh,
                                              const float* __restrict__ relw,
                                              u16* __restrict__ xt, u16* __restrict__ wqb,
                                              u16* __restrict__ wob, u16* __restrict__ relhb,
                                              u16* __restrict__ relwb) {
    int bid = blockIdx.x;
    int t = threadIdx.x;
    if (bid < 512) {
        int pm = bid & 63, cm = (bid >> 6) & 3, b = bid >> 8;
        int p0 = pm * 64, c0 = cm * 64;
        __shared__ float tile[64][65];
#pragma unroll
        for (int it = 0; it < 4; ++it) {
            int idx = it * 256 + t;
            int cl = idx >> 4, f4 = idx & 15;
            f32x4 v = *(const f32x4*)(x + ((size_t)(b * 256 + c0 + cl)) * 4096 + p0 + f4 * 4);
            tile[cl][f4 * 4 + 0] = v[0];
            tile[cl][f4 * 4 + 1] = v[1];
            tile[cl][f4 * 4 + 2] = v[2];
            tile[cl][f4 * 4 + 3] = v[3];
        }
        __syncthreads();
#pragma unroll
        for (int it = 0; it < 2; ++it) {
            int idx = it * 256 + t;
            int pl = idx >> 3, g = idx & 7;
            u32x4 pk;
            pk.x = pack2(tile[g * 8 + 0][pl], tile[g * 8 + 1][pl]);
            pk.y = pack2(tile[g * 8 + 2][pl], tile[g * 8 + 3][pl]);
            pk.z = pack2(tile[g * 8 + 4][pl], tile[g * 8 + 5][pl]);
            pk.w = pack2(tile[g * 8 + 6][pl], tile[g * 8 + 7][pl]);
            *(u32x4*)(xt + ((size_t)(b * 4096 + p0 + pl)) * 256 + c0 + g * 8) = pk;
        }
    } else {
        int i0 = (bid - 512) * 256 + t;  // 65536 stride
#pragma unroll
        for (int i = i0; i < 196608; i += 65536) wqb[i] = f2bf(wq[i]);
        if (i0 < 65536) wob[i0] = f2bf(wo[i0]);
        if (i0 < 8192) {
            relhb[i0] = (i0 < 8128) ? f2bf(relh[i0]) : (u16)0;
            relwb[i0] = (i0 < 8128) ? f2bf(relw[i0]) : (u16)0;
        }
    }
}

// ---------------------------------------------------------------------------
// K1: QKV projection GEMM + fused rel-bias tables, CONSOLIDATED: one block
// per (pm, head, b) computes ALL THREE tensors (V, K, then Q+rel-bias).
// Fixes the 3-4x load imbalance of the old (64,12,2) grid (the 256 tensor==0
// blocks dominated the 6-wave scheduling tail); 512 uniform blocks = 2/CU.
// areg loaded ONCE (xt reads 48 -> 16 MB). Sm reused per tensor (barrier at
// each staging top). Height table stored TRANSPOSED via LDS + coalesced.
__global__ __launch_bounds__(256) void k_qkv(const u16* __restrict__ xt, const u16* __restrict__ wqb,
                                             const u16* __restrict__ relwb,
                                             const u16* __restrict__ relhb,
                                             u16* __restrict__ q, u16* __restrict__ k,
                                             u16* __restrict__ vt, u16* __restrict__ Wabs,
                                             u16* __restrict__ HabsT) {
    int pm = blockIdx.x, head = blockIdx.y, b = blockIdx.z;
    int p0 = pm * 64;
    __shared__ __align__(16) u16 Sm[64 * 256];  // 32 KB B-tile; later T[64*72]+Ls[128*72]
    int t = threadIdx.x;
    int wv = t >> 6, l = t & 63, quad = l >> 4, li = l & 15;
    int bh = b * 4 + head;

    u32x4 areg[8];
    const u32x4* arow = (const u32x4*)(xt + ((size_t)(b * 4096 + p0 + wv * 16 + li)) * 256);
#pragma unroll
    for (int kc = 0; kc < 8; ++kc) areg[kc] = arow[kc * 4 + quad];

#pragma unroll
    for (int ti = 0; ti < 3; ++ti) {
        int tensor = 2 - ti;  // V, K, Q(+rel-bias last)
        int o0 = (tensor * 4 + head) * 64;
        __syncthreads();  // prior Sm reads done before staging overwrites
        {
            int pc = l & 31;
#pragma unroll
            for (int i = 0; i < 8; ++i) {
                int r = wv * 16 + i * 2 + (l >> 5);
                gll16(wqb + (size_t)(o0 + r) * 256 + ((pc + r) & 31) * 8,
                      Sm + (wv * 16 + i * 2) * 256);
            }
        }
        WAIT_VM0();
        __syncthreads();

        f32x4 acc[4] = {{0, 0, 0, 0}, {0, 0, 0, 0}, {0, 0, 0, 0}, {0, 0, 0, 0}};
#pragma unroll
        for (int kc = 0; kc < 8; ++kc) {
            bf16x8 a = bc8(areg[kc]);
#pragma unroll
            for (int ct = 0; ct < 4; ++ct) {
                bf16x8 bb = bc8(*(const u32x4*)(Sm + (ct * 16 + li) * 256 +
                                                (((kc * 4 + quad) - (ct * 16 + li)) & 31) * 8));
                acc[ct] = MFMA16(a, bb, acc[ct]);
            }
        }

        if (tensor == 2) {
            __syncthreads();
            u16* T = Sm;  // [64 d][72 p]
#pragma unroll
            for (int ct = 0; ct < 4; ++ct)
#pragma unroll
                for (int r = 0; r < 4; ++r)
                    T[(ct * 16 + li) * 72 + wv * 16 + quad * 4 + r] = f2bf(acc[ct][r]);
            __syncthreads();
            int dr = t >> 2, pc = (t & 3) * 16;
            u32x4* g = (u32x4*)(vt + ((size_t)(bh * 64 + dr)) * 4096 + p0 + pc);
            const u32x4* s2 = (const u32x4*)(T + dr * 72 + pc);
            g[0] = s2[0];
            g[1] = s2[1];
        } else if (tensor == 1) {
#pragma unroll
            for (int ct = 0; ct < 4; ++ct)
#pragma unroll
                for (int r = 0; r < 4; ++r) {
                    int p = p0 + wv * 16 + quad * 4 + r;
                    int d = ct * 16 + li;
                    k[((size_t)(bh * 4096 + p)) * 64 + d] = f2bf(acc[ct][r]);
                }
        } else {
#pragma unroll
            for (int ct = 0; ct < 4; ++ct)
#pragma unroll
                for (int r = 0; r < 4; ++r) {
                    int p = p0 + wv * 16 + quad * 4 + r;
                    int d = ct * 16 + li;
                    q[((size_t)(bh * 4096 + p)) * 64 + d] = f2bf(acc[ct][r] * QSCALE);
                }
            // ---- fused rel-bias tables ----
            u16* T = Sm;             // [64 p][72 d]
            u16* Ls = Sm + 64 * 72;  // [128 r][72 d]
            __syncthreads();  // all GEMM Sm reads done
#pragma unroll
            for (int ct = 0; ct < 4; ++ct)
#pragma unroll
                for (int r = 0; r < 4; ++r)
                    T[(wv * 16 + quad * 4 + r) * 72 + ct * 16 + li] = f2bf(acc[ct][r] * QSCALE);
            {
                int row = t >> 1, half = t & 1;
                const u32x4* g2 = (const u32x4*)(relwb + row * 64 + half * 32);
                u32x4* s2 = (u32x4*)(Ls + row * 72 + half * 32);
#pragma unroll
                for (int kk = 0; kk < 4; ++kk) s2[kk] = g2[kk];
            }
            __syncthreads();
            u32x4 aq2[2];
            aq2[0] = *(const u32x4*)(T + (wv * 16 + li) * 72 + quad * 8);
            aq2[1] = *(const u32x4*)(T + (wv * 16 + li) * 72 + 32 + quad * 8);

            f32x4 acc2[8];
#pragma unroll
            for (int ct = 0; ct < 8; ++ct) acc2[ct] = (f32x4){0.f, 0.f, 0.f, 0.f};
#pragma unroll
            for (int kc = 0; kc < 2; ++kc) {
                bf16x8 a = bc8(aq2[kc]);
#pragma unroll
                for (int ct = 0; ct < 8; ++ct) {
                    bf16x8 bb =
                        bc8(*(const u32x4*)(Ls + (ct * 16 + li) * 72 + kc * 32 + quad * 8));
                    acc2[ct] = MFMA16(a, bb, acc2[ct]);
                }
            }
#pragma unroll
            for (int ct = 0; ct < 8; ++ct)
#pragma unroll
                for (int r = 0; r < 4; ++r) {
                    int row = wv * 16 + quad * 4 + r;
                    int j = (ct * 16 + li) - 63 + row;  // shift = y = row
                    if (j >= 0 && j < 64)
                        Wabs[((size_t)(bh * 4096 + p0 + row)) * 64 + j] = f2bf(acc2[ct][r]);
                }
            __syncthreads();  // Ls reads done
            {
                int row = t >> 1, half = t & 1;
                const u32x4* g2 = (const u32x4*)(relhb + row * 64 + half * 32);
                u32x4* s2 = (u32x4*)(Ls + row * 72 + half * 32);
#pragma unroll
                for (int kk = 0; kk < 4; ++kk) s2[kk] = g2[kk];
            }
            __syncthreads();
#pragma unroll
            for (int ct = 0; ct < 8; ++ct) acc2[ct] = (f32x4){0.f, 0.f, 0.f, 0.f};
#pragma unroll
            for (int kc = 0; kc < 2; ++kc) {
                bf16x8 a = bc8(aq2[kc]);
#pragma unroll
                for (int ct = 0; ct < 8; ++ct) {
                    bf16x8 bb =
                        bc8(*(const u32x4*)(Ls + (ct * 16 + li) * 72 + kc * 32 + quad * 8));
                    acc2[ct] = MFMA16(a, bb, acc2[ct]);
                }
            }
            // transpose height bias in LDS (reuse dead T region), then store
            // HabsT[bh][jh][p] with coalesced u32x4 stores (vt-path pattern).
            u16* Ht = Sm;  // [64 j][72 p]
#pragma unroll
            for (int ct = 0; ct < 8; ++ct)
#pragma unroll
                for (int r = 0; r < 4; ++r) {
                    int row = wv * 16 + quad * 4 + r;
                    int j = (ct * 16 + li) - 63 + pm;  // shift = x = pm
                    if (j >= 0 && j < 64) Ht[j * 72 + row] = f2bf(acc2[ct][r]);
                }
            __syncthreads();
            {
                int jr = t >> 2, pc2 = (t & 3) * 16;
                u32x4* g2 = (u32x4*)(HabsT + ((size_t)(bh * 64 + jr)) * 4096 + p0 + pc2);
                const u32x4* s2 = (const u32x4*)(Ht + jr * 72 + pc2);
                g2[0] = s2[0];
                g2[1] = s2[1];
            }
        }
    }
}

// ---------------------------------------------------------------------------
// K3: flash attention (R11 banked best: 49.2us, VGPR 124, 0 conflicts, no
// spill). 4 rs/wave, gll staging + XOR slot-swizzle, grid (16,8,4). All
// scheduling levers measured-dead: occupancy (R2/R6/R10), P-pipelining (R8),
// barrier-halving (R12). Latency-bound plateau; structure frozen.
__global__ __launch_bounds__(256, 2) void k_flash(const u16* __restrict__ q,
                                                  const u16* __restrict__ kg,
                                                  const u16* __restrict__ vt,
                                                  const u16* __restrict__ Wabs,
                                                  const u16* __restrict__ HabsT,
                                                  u16* __restrict__ OP,
                                                  float* __restrict__ LS) {
    int pm = blockIdx.x, bh = blockIdx.y, ks = blockIdx.z;  // ks in 0..3
    int p0 = pm * 256;
    __shared__ __align__(16) u16 Kt[2][64 * 64];
    __shared__ __align__(16) u16 Vl[2][64 * 64];
    int t = threadIdx.x, wv = t >> 6, l = t & 63, quad = l >> 4, li = l & 15;
    int rbase = wv * 64;

    // Q B-frags for all four row-sets
    u32x4 aq[4][2];
#pragma unroll
    for (int rs = 0; rs < 4; ++rs) {
        const u32x4* qrow =
            (const u32x4*)(q + ((size_t)(bh * 4096 + p0 + rbase + rs * 16 + li)) * 64);
        aq[rs][0] = qrow[quad];
        aq[rs][1] = qrow[4 + quad];
    }

    // width-bias UNPACKED f32x4 per (rs,ct); C-frag slot (ct,quad,r) holds
    // original jw = (ct>>1)*32 + quad*8 + (ct&1)*4 + r  (sigma mapping)
    f32x4 wb4[4][4];
#pragma unroll
    for (int rs = 0; rs < 4; ++rs)
#pragma unroll
        for (int ct = 0; ct < 4; ++ct) {
            int jcol = ((ct >> 1) * 32) + quad * 8 + ((ct & 1) * 4);
            const u32* wp = (const u32*)(Wabs +
                                         ((size_t)(bh * 4096 + p0 + rbase + rs * 16 + li)) * 64 +
                                         jcol);
            u32 lo = wp[0], hi = wp[1];
            wb4[rs][ct] = (f32x4){bflo(lo), bfhi(lo), bflo(hi), bfhi(hi)};
        }

    // height-bias source: HabsT[bh][jh][p]
    const u16* hbase = HabsT + ((size_t)(bh * 64 + ks * 16)) * 4096 + p0 + rbase;

    // gll source mapping: lane l writes LDS phys row R = n*32 + wv*8 + (l>>3),
    // 16B slot (l&7). K: global row sigma^-1(R), col slot (l&7)^(l>>3).
    int ln3 = l >> 3, ln7 = l & 7;
    int xo = (ln7 ^ ln3) * 8;  // u16 col offset
    int R0 = wv * 8 + ln3, R1 = 32 + R0;
    int j0r = (R0 & 32) | ((R0 & 16) >> 2) | ((R0 & 8) << 1) | ((R0 & 4) << 1) | (R0 & 3);
    int j1r = (R1 & 32) | ((R1 & 16) >> 2) | ((R1 & 8) << 1) | ((R1 & 4) << 1) | (R1 & 3);
    const u16* kS0 = kg + ((size_t)(bh * 4096 + ks * 1024 + j0r)) * 64 + xo;
    const u16* kS1 = kg + ((size_t)(bh * 4096 + ks * 1024 + j1r)) * 64 + xo;
    const u16* vS0 = vt + ((size_t)(bh * 64 + R0)) * 4096 + ks * 1024 + xo;
    const u16* vS1 = vt + ((size_t)(bh * 64 + R1)) * 4096 + ks * 1024 + xo;
    int ldst = wv * 512;  // wave-uniform LDS u16 offset (call n adds n*2048)

    // ds_read offsets: addr = row*64 + ((grp)^(row&7))*8 ; row = blk*16+li
    int o0 = li * 64 + ((quad ^ ln7) * 8);        // kc/half = 0
    int o1 = li * 64 + (((quad + 4) ^ ln7) * 8);  // kc/half = 1

    // preload tile 0 into buffer 0
    gll16(kS0, Kt[0] + ldst);
    gll16(kS1, Kt[0] + 2048 + ldst);
    gll16(vS0, Vl[0] + ldst);
    gll16(vS1, Vl[0] + 2048 + ldst);
    u16 hc[4];
#pragma unroll
    for (int rs = 0; rs < 4; ++rs) hc[rs] = hbase[rs * 16 + li];
    WAIT_VM0();

    f32x4 oacc[4][5];
#pragma unroll
    for (int rs = 0; rs < 4; ++rs)
#pragma unroll
        for (int ct = 0; ct < 5; ++ct) oacc[rs][ct] = (f32x4){0.f, 0.f, 0.f, 0.f};

    const u32x4 ones = {0x3F803F80u, 0x3F803F80u, 0x3F803F80u, 0x3F803F80u};

    for (int kt = 0; kt < 16; ++kt) {
        __syncthreads();  // tile kt ready in buf[kt&1]; prior reads of buf[kt^1] done
        int cur = kt & 1;
        const u16* Kc = Kt[cur];
        const u16* Vc = Vl[cur];
        u16 hn[4];
        if (kt < 15) {
            kS0 += 4096;
            kS1 += 4096;
            vS0 += 64;
            vS1 += 64;
            u16* Kn = Kt[cur ^ 1];
            u16* Vn = Vl[cur ^ 1];
            gll16(kS0, Kn + ldst);
            gll16(kS1, Kn + 2048 + ldst);
            gll16(vS0, Vn + ldst);
            gll16(vS1, Vn + 2048 + ldst);
#pragma unroll
            for (int rs = 0; rs < 4; ++rs) hn[rs] = hbase[(size_t)(kt + 1) * 4096 + rs * 16 + li];
        }

        // hoisted per-iter height-bias converts (4 instead of 16)
        float hh[4];
#pragma unroll
        for (int rs = 0; rs < 4; ++rs) hh[rs] = bf2f(hc[rs]);

        // S^T = K · Q^T (bias-init accumulators), exp2 + pack per (ct,rs)
        u32x4 pf[4][2];
#pragma unroll
        for (int ct = 0; ct < 4; ++ct) {
            bf16x8 af0 = bc8(*(const u32x4*)(Kc + ct * 1024 + o0));
            bf16x8 af1 = bc8(*(const u32x4*)(Kc + ct * 1024 + o1));
#pragma unroll
            for (int rs = 0; rs < 4; ++rs) {
                f32x4 hv = {hh[rs], hh[rs], hh[rs], hh[rs]};
                f32x4 s4 = wb4[rs][ct] + hv;
                s4 = MFMA16(af0, bc8(aq[rs][0]), s4);
                s4 = MFMA16(af1, bc8(aq[rs][1]), s4);
                u32 pa = pack2(EXP2F(s4[0]), EXP2F(s4[1]));
                u32 pb = pack2(EXP2F(s4[2]), EXP2F(s4[3]));
                if (ct & 1) {
                    pf[rs][ct >> 1].z = pa;
                    pf[rs][ct >> 1].w = pb;
                } else {
                    pf[rs][ct >> 1].x = pa;
                    pf[rs][ct >> 1].y = pb;
                }
            }
        }

        // O += P · V via MFMA16 (K=32); setprio(1) around the MFMA cluster
        __builtin_amdgcn_s_setprio(1);
#pragma unroll
        for (int dt = 0; dt < 4; ++dt) {
            bf16x8 B0 = bc8(*(const u32x4*)(Vc + dt * 1024 + o0));
            bf16x8 B1 = bc8(*(const u32x4*)(Vc + dt * 1024 + o1));
#pragma unroll
            for (int rs = 0; rs < 4; ++rs) {
                oacc[rs][dt] = MFMA16(bc8(pf[rs][0]), B0, oacc[rs][dt]);
                oacc[rs][dt] = MFMA16(bc8(pf[rs][1]), B1, oacc[rs][dt]);
            }
        }
        // row sums via ones operand
#pragma unroll
        for (int rs = 0; rs < 4; ++rs) {
            oacc[rs][4] = MFMA16(bc8(pf[rs][0]), bc8(ones), oacc[rs][4]);
            oacc[rs][4] = MFMA16(bc8(pf[rs][1]), bc8(ones), oacc[rs][4]);
        }
        __builtin_amdgcn_s_setprio(0);

        if (kt < 15) {
            WAIT_VM0();  // gll writes to buf[cur^1] + hn loads landed
#pragma unroll
            for (int rs = 0; rs < 4; ++rs) hc[rs] = hn[rs];
        }
    }

    // store bf16 partials + fp32 row-sums (normalization in k_out2)
#pragma unroll
    for (int rs = 0; rs < 4; ++rs) {
#pragma unroll
        for (int ct = 0; ct < 4; ++ct)
#pragma unroll
            for (int r = 0; r < 4; ++r) {
                int p = p0 + rbase + rs * 16 + quad * 4 + r;
                OP[((size_t)((ks * 8 + bh) * 4096 + p)) * 64 + ct * 16 + li] =
                    f2bf(oacc[rs][ct][r]);
            }
        if (li == 0) {
#pragma unroll
            for (int r = 0; r < 4; ++r) {
                int p = p0 + rbase + rs * 16 + quad * 4 + r;
                LS[(size_t)(ks * 8 + bh) * 4096 + p] = oacc[rs][4][r];
            }
        }
    }
}

// ---------------------------------------------------------------------------
// K4: fused combine (4 K-slices) + out-projection + residual, v2.
// p split 128-way (32-row tiles), grid (128 pm, 2 b, 2 coh) = 512 blocks.
__global__ __launch_bounds__(256) void k_out2(const u16* __restrict__ wob,
                                              const u16* __restrict__ OP,
                                              const float* __restrict__ LS,
                                              const float* __restrict__ x,
                                              float* __restrict__ out) {
    int pm = blockIdx.x, b = blockIdx.y, coh = blockIdx.z;
    int p0 = pm * 32;
    __shared__ __align__(16) u16 Bt[32 * 264];
    int t = threadIdx.x, wv = t >> 6, l = t & 63, quad = l >> 4, li = l & 15;

    {
        int row = t >> 3, head = (t >> 1) & 3, hf = t & 1;
        int bh = b * 4 + head;
        int p = p0 + row;
        const u32x4* o0p = (const u32x4*)(OP + ((size_t)(bh * 4096 + p)) * 64) + hf * 4;
        const u32x4* o1p = (const u32x4*)(OP + ((size_t)((8 + bh) * 4096 + p)) * 64) + hf * 4;
        const u32x4* o2p = (const u32x4*)(OP + ((size_t)((16 + bh) * 4096 + p)) * 64) + hf * 4;
        const u32x4* o3p = (const u32x4*)(OP + ((size_t)((24 + bh) * 4096 + p)) * 64) + hf * 4;
        float linv = 1.0f / (LS[(size_t)bh * 4096 + p] + LS[(size_t)(8 + bh) * 4096 + p] +
                             LS[(size_t)(16 + bh) * 4096 + p] + LS[(size_t)(24 + bh) * 4096 + p]);
        u16* dst = Bt + row * 264 + head * 64 + hf * 32;
#pragma unroll
        for (int kk = 0; kk < 4; ++kk) {
            u32x4 a = o0p[kk], c = o1p[kk], d = o2p[kk], e = o3p[kk];
            u32x4 pk;
            pk.x = pack2((bflo(a.x) + bflo(c.x) + bflo(d.x) + bflo(e.x)) * linv,
                         (bfhi(a.x) + bfhi(c.x) + bfhi(d.x) + bfhi(e.x)) * linv);
            pk.y = pack2((bflo(a.y) + bflo(c.y) + bflo(d.y) + bflo(e.y)) * linv,
                         (bfhi(a.y) + bfhi(c.y) + bfhi(d.y) + bfhi(e.y)) * linv);
            pk.z = pack2((bflo(a.z) + bflo(c.z) + bflo(d.z) + bflo(e.z)) * linv,
                         (bfhi(a.z) + bfhi(c.z) + bfhi(d.z) + bfhi(e.z)) * linv);
            pk.w = pack2((bflo(a.w) + bflo(c.w) + bflo(d.w) + bflo(e.w)) * linv,
                         (bfhi(a.w) + bfhi(c.w) + bfhi(d.w) + bfhi(e.w)) * linv);
            *(u32x4*)(dst + kk * 8) = pk;
        }
    }
    __syncthreads();

#pragma unroll
    for (int ci = 0; ci < 2; ++ci) {
        int com = coh * 2 + ci;
        int co0 = com * 64;
        f32x4 acc[2] = {{0, 0, 0, 0}, {0, 0, 0, 0}};
        const u32x4* arow = (const u32x4*)(wob + (size_t)(co0 + wv * 16 + li) * 256);
#pragma unroll
        for (int kc = 0; kc < 8; ++kc) {
            bf16x8 a = bc8(arow[kc * 4 + quad]);
#pragma unroll
            for (int ct = 0; ct < 2; ++ct) {
                bf16x8 bb = bc8(*(const u32x4*)(Bt + (ct * 16 + li) * 264 + kc * 32 + quad * 8));
                acc[ct] = MFMA16(a, bb, acc[ct]);
            }
        }
#pragma unroll
        for (int ct = 0; ct < 2; ++ct)
#pragma unroll
            for (int r = 0; r < 4; ++r) {
                size_t idx =
                    ((size_t)(b * 256 + co0 + wv * 16 + quad * 4 + r)) * 4096 + p0 + ct * 16 + li;
                out[idx] = acc[ct][r] + x[idx];
            }
    }
}

// ---------------------------------------------------------------------------
extern "C" void kernel_launch(void* const* d_in, const int* in_sizes, int n_in, void* d_out,
                              int out_size, void* d_ws, size_t ws_size, hipStream_t stream) {
    const float* x = (const float*)d_in[0];
    const float* wqkv = (const float*)d_in[1];
    const float* wout = (const float*)d_in[2];
    const float* relh = (const float*)d_in[3];
    const float* relw = (const float*)d_in[4];
    float* out = (float*)d_out;
    char* ws = (char*)d_ws;

    u16* xt = (u16*)(ws + 0);               // 4,194,304 (dead after k_qkv)
    u16* wqb = (u16*)(ws + 4194304);        //   393,216
    u16* wob = (u16*)(ws + 4587520);        //   131,072
    u16* relwb = (u16*)(ws + 4718592);      //    16,384
    u16* relhb = (u16*)(ws + 4734976);      //    16,384
    u16* qb = (u16*)(ws + 4751360);         // 4,194,304
    u16* kb = (u16*)(ws + 8945664);         // 4,194,304
    u16* vtb = (u16*)(ws + 13139968);       // 4,194,304
    u16* Wabs = (u16*)(ws + 17334272);      // 4,194,304
    u16* HabsT = (u16*)(ws + 21528576);     // 4,194,304
    u16* OPart = (u16*)(ws + 25722880);     // 16,777,216 (4 x 8 x 4096 x 64 bf16)
    float* LSum = (float*)(ws + 0);         //   524,288 (aliases dead xt)

    k_prep<<<768, 256, 0, stream>>>(x, wqkv, wout, relh, relw, xt, wqb, wob, relhb, relwb);
    k_qkv<<<dim3(64, 4, 2), 256, 0, stream>>>(xt, wqb, relwb, relhb, qb, kb, vtb, Wabs, HabsT);
    k_flash<<<dim3(16, 8, 4), 256, 0, stream>>>(qb, kb, vtb, Wabs, HabsT, OPart, LSum);
    k_out2<<<dim3(128, 2, 2), 256, 0, stream>>>(wob, OPart, LSum, x, out);
}